// Round 2
// baseline (297.835 us; speedup 1.0000x reference)
//
#include <hip/hip_runtime.h>

// Problem shape is fixed by the reference harness:
// image: [8, 512, 512, 16] f32, flow: [8, 512, 512, 2] f32 -> out: [8, 512, 512, 16] f32
constexpr int B = 8;
constexpr int H = 512;
constexpr int W = 512;
constexpr int C = 16;
constexpr int NPIX = B * H * W;

__device__ __forceinline__ float4 lerp4(float4 a, float4 b, float t) {
    float4 r;
    r.x = a.x + t * (b.x - a.x);
    r.y = a.y + t * (b.y - a.y);
    r.z = a.z + t * (b.z - a.z);
    r.w = a.w + t * (b.w - a.w);
    return r;
}

__global__ __launch_bounds__(256) void warp_bilinear_kernel(
    const float* __restrict__ image,
    const float* __restrict__ flow,
    float* __restrict__ out) {

    int idx = blockIdx.x * blockDim.x + threadIdx.x;  // pixel index over B*H*W
    if (idx >= NPIX) return;

    int x = idx & (W - 1);          // W = 512 = 2^9
    int y = (idx >> 9) & (H - 1);   // H = 512
    int b = idx >> 18;

    // flow[..., 0] = dy, flow[..., 1] = dx ; query = grid - flow
    float2 f = *reinterpret_cast<const float2*>(flow + (size_t)idx * 2);
    float qy = (float)y - f.x;
    float qx = (float)x - f.y;

    // floor clipped to [0, size-2]; alpha clipped to [0, 1]  (edge clamp)
    float fy = fminf(fmaxf(floorf(qy), 0.0f), (float)(H - 2));
    float fx = fminf(fmaxf(floorf(qx), 0.0f), (float)(W - 2));
    float ay = fminf(fmaxf(qy - fy, 0.0f), 1.0f);
    float ax = fminf(fmaxf(qx - fx, 0.0f), 1.0f);
    int iy = (int)fy;
    int ix = (int)fx;

    const float* basep = image + ((((size_t)b * H + iy) * W) + ix) * C;
    const float4* tl4 = reinterpret_cast<const float4*>(basep);
    const float4* tr4 = reinterpret_cast<const float4*>(basep + C);
    const float4* bl4 = reinterpret_cast<const float4*>(basep + (size_t)W * C);
    const float4* br4 = reinterpret_cast<const float4*>(basep + (size_t)W * C + C);
    float4* o4 = reinterpret_cast<float4*>(out + (size_t)idx * C);

#pragma unroll
    for (int g = 0; g < 4; ++g) {   // 16 channels as 4x float4
        float4 tl = tl4[g];
        float4 tr = tr4[g];
        float4 bl = bl4[g];
        float4 br = br4[g];
        float4 top = lerp4(tl, tr, ax);
        float4 bot = lerp4(bl, br, ax);
        o4[g] = lerp4(top, bot, ay);
    }
}

extern "C" void kernel_launch(void* const* d_in, const int* in_sizes, int n_in,
                              void* d_out, int out_size, void* d_ws, size_t ws_size,
                              hipStream_t stream) {
    const float* image = (const float*)d_in[0];
    const float* flow  = (const float*)d_in[1];
    float* out = (float*)d_out;

    constexpr int block = 256;
    constexpr int grid = (NPIX + block - 1) / block;  // 8192 blocks
    warp_bilinear_kernel<<<grid, block, 0, stream>>>(image, flow, out);
}

// Round 4
// 253.889 us; speedup vs baseline: 1.1731x; 1.1731x over previous
//
#include <hip/hip_runtime.h>

// image: [8, 512, 512, 16] f32, flow: [8, 512, 512, 2] f32 -> out: [8, 512, 512, 16] f32
constexpr int B = 8;
constexpr int H = 512;
constexpr int W = 512;
constexpr int C = 16;
constexpr int NPIX = B * H * W;            // 2,097,152 pixels
constexpr int NTHREADS = NPIX * 4;         // 4 threads per pixel (one float4 group each)
constexpr int BLOCK = 256;
constexpr int NBLOCKS = NTHREADS / BLOCK;  // 32768, divisible by 8 XCDs
constexpr int NXCD = 8;

// clang-native 4-float vector — required by __builtin_nontemporal_store
// (HIP's float4 is a class type the builtin rejects).
typedef float f4 __attribute__((ext_vector_type(4)));

__device__ __forceinline__ f4 lerp4(f4 a, f4 b, float t) {
    return a + t * (b - a);
}

__global__ __launch_bounds__(256) void warp_bilinear_kernel(
    const float* __restrict__ image,
    const float* __restrict__ flow,
    float* __restrict__ out) {

    // XCD-contiguous swizzle: hardware round-robins blocks across 8 XCDs;
    // remap so XCD k processes logical blocks [k*NB/8, (k+1)*NB/8) — each XCD
    // owns one contiguous batch image, keeping row y / y+1 reuse in one L2.
    int bid = blockIdx.x;
    int swz = (bid & (NXCD - 1)) * (NBLOCKS / NXCD) + (bid >> 3);

    int tid = swz * BLOCK + threadIdx.x;
    int g = tid & 3;         // channel group: 4 floats each
    int p = tid >> 2;        // pixel index over B*H*W

    int x = p & (W - 1);
    int y = (p >> 9) & (H - 1);
    int b = p >> 18;

    // flow[...,0]=dy, flow[...,1]=dx ; query = grid - flow
    // 4 lanes of the same pixel read the same float2 (same cache line — free).
    float2 f = *reinterpret_cast<const float2*>(flow + (size_t)p * 2);
    float qy = (float)y - f.x;
    float qx = (float)x - f.y;

    float fy = fminf(fmaxf(floorf(qy), 0.0f), (float)(H - 2));
    float fx = fminf(fmaxf(floorf(qx), 0.0f), (float)(W - 2));
    float ay = fminf(fmaxf(qy - fy, 0.0f), 1.0f);
    float ax = fminf(fmaxf(qx - fx, 0.0f), 1.0f);
    int iy = (int)fy;
    int ix = (int)fx;

    const f4* base =
        reinterpret_cast<const f4*>(image + ((((size_t)b * H + iy) * W) + ix) * C);
    // row stride in f4 units: W*C/4 = 2048
    f4 tl = base[g];
    f4 tr = base[4 + g];
    f4 bl = base[(W * C / 4) + g];
    f4 br = base[(W * C / 4) + 4 + g];

    f4 top = lerp4(tl, tr, ax);
    f4 bot = lerp4(bl, br, ax);
    f4 res = lerp4(top, bot, ay);

    // write-once output: non-temporal to avoid evicting image lines
    f4* o = reinterpret_cast<f4*>(out + (size_t)p * C) + g;
    __builtin_nontemporal_store(res, o);
}

extern "C" void kernel_launch(void* const* d_in, const int* in_sizes, int n_in,
                              void* d_out, int out_size, void* d_ws, size_t ws_size,
                              hipStream_t stream) {
    const float* image = (const float*)d_in[0];
    const float* flow  = (const float*)d_in[1];
    float* out = (float*)d_out;

    warp_bilinear_kernel<<<NBLOCKS, BLOCK, 0, stream>>>(image, flow, out);
}